// Round 4
// baseline (193.769 us; speedup 1.0000x reference)
//
#include <hip/hip_runtime.h>

typedef unsigned short u16;
typedef unsigned int u32;
typedef __attribute__((ext_vector_type(8))) short s16x8;   // 8 bf16 (4 VGPRs) MFMA A/B frag
typedef __attribute__((ext_vector_type(4))) float f32x4;   // MFMA C/D frag

#define DIM    1024
#define NHEADS 16
#define HD     64
#define NSEQ   2048
#define QKVN   3072

__device__ __forceinline__ u16 f2bf(float f) {
  u32 u = __float_as_uint(f);
  u += 0x7FFF + ((u >> 16) & 1);   // RNE
  return (u16)(u >> 16);
}

// raw v_exp_f32 (exp2). HIP's exp2f() is precise libm (~10 ops) — r3 regression.
__device__ __forceinline__ float vexp2(float x) {
  float r;
  asm volatile("v_exp_f32 %0, %1" : "=v"(r) : "v"(x));
  return r;
}

// async global->LDS, 16B per lane. LDS dst = wave-uniform base + lane*16.
__device__ __forceinline__ void async16(const u16* g, u16* l) {
  __builtin_amdgcn_global_load_lds(
      (const __attribute__((address_space(1))) unsigned int*)g,
      (__attribute__((address_space(3))) unsigned int*)l, 16, 0, 0);
}

// ---------------------------------------------------------------- cast fp32 -> bf16
__global__ void cast_all(const float* __restrict__ x, const float* __restrict__ wq,
                         const float* __restrict__ wp, u16* __restrict__ xo,
                         u16* __restrict__ wqo, u16* __restrict__ wpo) {
  int i = blockIdx.x * 256 + threadIdx.x;        // 2,097,152 threads, 4 floats each
  const float4* src; u16* dst; int off;
  if (i < 1048576)      { src = (const float4*)x;  dst = xo;  off = i; }
  else if (i < 1835008) { src = (const float4*)wq; dst = wqo; off = i - 1048576; }
  else                  { src = (const float4*)wp; dst = wpo; off = i - 1835008; }
  float4 f = src[off];
  ushort4 o;
  o.x = f2bf(f.x); o.y = f2bf(f.y); o.z = f2bf(f.z); o.w = f2bf(f.w);
  ((ushort4*)dst)[off] = o;
}

// ---------------------------------------------------------------- GEMM  C = A * B^T
// A [M,1024] bf16 K-major, B [N,1024] bf16 K-major. BK=64, async staging with
// XOR chunk swizzle c' = c ^ (row&7). MODE 0: QK band (n0 0..2047), transposed
// MFMA (Cᵀ) -> packed ushort4 stores into qkv. MODE 1: V band (n0 2048..3071),
// normal MFMA -> packed ushort4 into vt[bh][hd][tok]. MODE 2: out = C + bias,
// transposed MFMA -> float4 stores.
template <int MODE>
__global__ __launch_bounds__(256, 3) void gemm_bt(
    const u16* __restrict__ A, const u16* __restrict__ Bw, u16* __restrict__ qkv,
    u16* __restrict__ vt, const float* __restrict__ bias, float* __restrict__ outp) {
  constexpr int K = 1024;
  constexpr int BM = (MODE == 0) ? 128 : 64;
  constexpr int MT = (MODE == 0) ? 32 : 64;
  constexpr int IT = (MODE == 0) ? 4 : 2;     // 16-row i-tiles per wave
  constexpr int ACALLS = BM / 8;              // wave-calls to stage A tile
  constexpr int TCALLS = ACALLS + 16;
  constexpr int PW = TCALLS / 4;              // calls per wave
  constexpr bool TRANS = (MODE != 1);
  const int bm = blockIdx.x % MT;
  const int bn = blockIdx.x / MT;
  const int tid = threadIdx.x;
  const int wave = tid >> 6, lane = tid & 63;
  const int q4 = lane >> 4, l15 = lane & 15;
  const int wm = wave >> 1, wn = wave & 1;
  const int m0 = bm * BM;
  const int n0 = (MODE == 1 ? 2048 : 0) + bn * 128;

  __shared__ alignas(16) u16 lsA[BM * 64];
  __shared__ alignas(16) u16 lsB[128 * 64];

  f32x4 acc[IT][4];
#pragma unroll
  for (int i = 0; i < IT; i++)
#pragma unroll
    for (int j = 0; j < 4; j++) acc[i][j] = (f32x4){0.f, 0.f, 0.f, 0.f};

  for (int k0 = 0; k0 < K; k0 += 64) {
    __syncthreads();
#pragma unroll
    for (int j = 0; j < PW; ++j) {
      int t = wave * PW + j;
      if (t < ACALLS) {
        int lin = t * 64 + lane;
        int r = lin >> 3, cs = lin & 7, c = cs ^ (r & 7);
        async16(A + (size_t)(m0 + r) * K + k0 + c * 8, lsA + t * 512);
      } else {
        int tb = t - ACALLS;
        int lin = tb * 64 + lane;
        int r = lin >> 3, cs = lin & 7, c = cs ^ (r & 7);
        async16(Bw + (size_t)(n0 + r) * K + k0 + c * 8, lsB + tb * 512);
      }
    }
    __syncthreads();
#pragma unroll
    for (int kc = 0; kc < 2; ++kc) {
      s16x8 af[IT], bfr[4];
#pragma unroll
      for (int i = 0; i < IT; ++i) {
        int r = wm * (IT * 16) + i * 16 + l15;
        int c = (kc * 4 + q4) ^ (r & 7);
        af[i] = *(const s16x8*)(lsA + r * 64 + c * 8);
      }
#pragma unroll
      for (int j = 0; j < 4; ++j) {
        int r = wn * 64 + j * 16 + l15;
        int c = (kc * 4 + q4) ^ (r & 7);
        bfr[j] = *(const s16x8*)(lsB + r * 64 + c * 8);
      }
#pragma unroll
      for (int i = 0; i < IT; ++i)
#pragma unroll
        for (int j = 0; j < 4; ++j) {
          if (TRANS)   // Cᵀ: rows = n-dim, cols = m-dim (A/B frag layouts symmetric)
            acc[i][j] = __builtin_amdgcn_mfma_f32_16x16x32_bf16(bfr[j], af[i], acc[i][j], 0, 0, 0);
          else
            acc[i][j] = __builtin_amdgcn_mfma_f32_16x16x32_bf16(af[i], bfr[j], acc[i][j], 0, 0, 0);
        }
    }
  }

  // epilogue
#pragma unroll
  for (int i = 0; i < IT; i++) {
#pragma unroll
    for (int j = 0; j < 4; j++) {
      if (MODE == 2) {           // Cᵀ: lane = token m, regs = 4 consecutive n
        int m = m0 + wm * (IT * 16) + i * 16 + l15;
        int nb = n0 + wn * 64 + j * 16 + q4 * 4;
        float4 bv = *(const float4*)(bias + nb);
        float4 v = {acc[i][j][0] + bv.x, acc[i][j][1] + bv.y,
                    acc[i][j][2] + bv.z, acc[i][j][3] + bv.w};
        *(float4*)(outp + (size_t)m * DIM + nb) = v;
      } else if (MODE == 0) {    // Cᵀ: packed 4 d-cols per token
        int m = m0 + wm * (IT * 16) + i * 16 + l15;
        int nb = n0 + wn * 64 + j * 16 + q4 * 4;
        ushort4 pk;
        pk.x = f2bf(acc[i][j][0]); pk.y = f2bf(acc[i][j][1]);
        pk.z = f2bf(acc[i][j][2]); pk.w = f2bf(acc[i][j][3]);
        *(ushort4*)(qkv + (size_t)m * QKVN + nb) = pk;
      } else {                   // normal: regs = 4 consecutive tokens, packed into vt
        int n = n0 + wn * 64 + j * 16 + l15;
        int mb = m0 + wm * (IT * 16) + i * 16 + q4 * 4;
        int b = mb >> 11, tok = mb & 2047;
        int h = (n >> 6) & 15, hd = n & 63;
        ushort4 pk;
        pk.x = f2bf(acc[i][j][0]); pk.y = f2bf(acc[i][j][1]);
        pk.z = f2bf(acc[i][j][2]); pk.w = f2bf(acc[i][j][3]);
        *(ushort4*)(vt + ((size_t)((b * NHEADS + h) * HD + hd)) * NSEQ + tok) = pk;
      }
    }
  }
}

// ---------------------------------------------------------------- flash attention
// 512 blocks (32 bh x 16 q-tiles of 128), 8 waves x 16 q-rows. 128-key staging
// tiles. exp2-domain softmax (Q pre-scaled by log2(e)/8, raw v_exp_f32).
// P truncated to bf16; lsum accumulates the truncated value (normalizer
// consistent with MFMA input -> no scale bias).
__global__ __launch_bounds__(512, 4) void attn_kernel(const u16* __restrict__ qkv,
                                                      const u16* __restrict__ vt,
                                                      u16* __restrict__ aout) {
  const int blk = blockIdx.x;            // 512 = 32 bh * 16 qtiles
  const int bh = blk >> 4, qt = blk & 15;
  const int b = bh >> 4, h = bh & 15;
  const int tid = threadIdx.x;
  const int wave = tid >> 6, lane = tid & 63;
  const int q4 = lane >> 4, l15 = lane & 15;

  __shared__ alignas(16) u16 lsK[128 * 64];      // [key][hd], swizzled 16B chunks
  __shared__ alignas(16) u16 lsV[64 * 128];      // [hd][key], swizzled 16B chunks
  __shared__ alignas(16) u16 lsP[8][16 * 72];    // per-wave P [qrow][key], stride 72

  // Q A-frags in registers, pre-scaled by log2(e)/8 (f32 mul, RNE back to bf16)
  const float QSCALE = 0.18033688011112042f;     // log2(e)/8
  s16x8 aq[2];
#pragma unroll
  for (int kc = 0; kc < 2; ++kc) {
    int row = b * NSEQ + qt * 128 + wave * 16 + l15;
    uint4 d = *(const uint4*)(qkv + (size_t)row * QKVN + h * HD + kc * 32 + q4 * 8);
    u32 w[4] = {d.x, d.y, d.z, d.w};
    s16x8 f;
#pragma unroll
    for (int j = 0; j < 8; ++j) {
      u16 u = (u16)(w[j >> 1] >> ((j & 1) * 16));
      float v = __uint_as_float(((u32)u) << 16) * QSCALE;
      f[j] = (short)f2bf(v);
    }
    aq[kc] = f;
  }

  f32x4 o[4];
  float lsum[4] = {0.f, 0.f, 0.f, 0.f};
#pragma unroll
  for (int ht = 0; ht < 4; ++ht) o[ht] = (f32x4){0.f, 0.f, 0.f, 0.f};

  for (int kt = 0; kt < 16; ++kt) {              // 128 keys per staging tile
    __syncthreads();
#pragma unroll
    for (int j = 0; j < 2; ++j) {
      int t = wave * 2 + j;
      int lin = t * 64 + lane;
      int rK = lin >> 3, cK = (lin & 7) ^ (rK & 7);
      async16(qkv + (size_t)(b * NSEQ + kt * 128 + rK) * QKVN + DIM + h * HD + cK * 8,
              lsK + t * 512);
      int rV = lin >> 4, cV = (lin & 15) ^ (rV & 15);
      async16(vt + (size_t)(bh * HD + rV) * NSEQ + kt * 128 + cV * 8,
              lsV + t * 512);
    }
    __syncthreads();

#pragma unroll
    for (int half = 0; half < 2; ++half) {
      // S = Q K^T  (16 q-rows x 64 keys per wave)
      f32x4 s[4];
#pragma unroll
      for (int ct = 0; ct < 4; ++ct) s[ct] = (f32x4){0.f, 0.f, 0.f, 0.f};
#pragma unroll
      for (int kc = 0; kc < 2; ++kc) {
#pragma unroll
        for (int ct = 0; ct < 4; ++ct) {
          int r = half * 64 + ct * 16 + l15;
          int c = (kc * 4 + q4) ^ (r & 7);
          s16x8 bk = *(const s16x8*)(lsK + r * 64 + c * 8);
          s[ct] = __builtin_amdgcn_mfma_f32_16x16x32_bf16(aq[kc], bk, s[ct], 0, 0, 0);
        }
      }

      // p = exp2(s) via raw v_exp_f32; truncate to bf16; lsum sums truncated value
#pragma unroll
      for (int ct = 0; ct < 4; ++ct)
#pragma unroll
        for (int r = 0; r < 4; ++r) {
          u32 u = __float_as_uint(vexp2(s[ct][r]));
          lsum[r] += __uint_as_float(u & 0xffff0000u);
          lsP[wave][(q4 * 4 + r) * 72 + ct * 16 + l15] = (u16)(u >> 16);
        }

      // O += P * V
#pragma unroll
      for (int kc = 0; kc < 2; ++kc) {
        s16x8 pa = *(const s16x8*)(lsP[wave] + l15 * 72 + kc * 32 + q4 * 8);
#pragma unroll
        for (int ht = 0; ht < 4; ++ht) {
          int r = ht * 16 + l15;
          int c = (half * 8 + kc * 4 + q4) ^ (r & 15);
          s16x8 vb = *(const s16x8*)(lsV + r * 128 + c * 8);
          o[ht] = __builtin_amdgcn_mfma_f32_16x16x32_bf16(pa, vb, o[ht], 0, 0, 0);
        }
      }
    }
  }

  // final row-sum reduction over the 16 l15 lanes
#pragma unroll
  for (int off = 1; off < 16; off <<= 1)
#pragma unroll
    for (int r = 0; r < 4; ++r) lsum[r] += __shfl_xor(lsum[r], off, 64);
  float inv[4];
#pragma unroll
  for (int r = 0; r < 4; ++r) inv[r] = 1.0f / lsum[r];

#pragma unroll
  for (int ht = 0; ht < 4; ++ht)
#pragma unroll
    for (int r = 0; r < 4; ++r) {
      int n = qt * 128 + wave * 16 + q4 * 4 + r;
      int col = h * HD + ht * 16 + l15;
      aout[(size_t)(b * NSEQ + n) * DIM + col] = f2bf(o[ht][r] * inv[r]);
    }
}

// ---------------------------------------------------------------- launch
extern "C" void kernel_launch(void* const* d_in, const int* in_sizes, int n_in,
                              void* d_out, int out_size, void* d_ws, size_t ws_size,
                              hipStream_t stream) {
  const float* x     = (const float*)d_in[0];
  const float* w_qkv = (const float*)d_in[1];
  const float* w_prj = (const float*)d_in[2];
  const float* b_prj = (const float*)d_in[3];
  float* out = (float*)d_out;

  char* ws = (char*)d_ws;
  u16* x_bf    = (u16*)(ws);                          // 8 MB
  u16* wqkv_bf = (u16*)(ws + (size_t)(8u << 20));     // 6 MB
  u16* wprj_bf = (u16*)(ws + (size_t)(14u << 20));    // 2 MB
  u16* qkv     = (u16*)(ws + (size_t)(16u << 20));    // 24 MB (Q,K used; V slot unused)
  u16* vt      = (u16*)(ws + (size_t)(40u << 20));    // 8 MB
  u16* aout    = (u16*)(ws + (size_t)(48u << 20));    // 8 MB   total 56 MB

  cast_all<<<8192, 256, 0, stream>>>(x, w_qkv, w_prj, x_bf, wqkv_bf, wprj_bf);
  gemm_bt<0><<<32 * 16, 256, 0, stream>>>(x_bf, wqkv_bf, qkv, vt, nullptr, nullptr);
  gemm_bt<1><<<64 * 8, 256, 0, stream>>>(x_bf, wqkv_bf, qkv, vt, nullptr, nullptr);
  attn_kernel<<<512, 512, 0, stream>>>(qkv, vt, aout);
  gemm_bt<2><<<64 * 8, 256, 0, stream>>>(aout, wprj_bf, nullptr, nullptr, b_prj, out);
}

// Round 5
// 189.373 us; speedup vs baseline: 1.0232x; 1.0232x over previous
//
#include <hip/hip_runtime.h>

typedef unsigned short u16;
typedef unsigned int u32;
typedef __attribute__((ext_vector_type(8))) short s16x8;   // 8 bf16 (4 VGPRs) MFMA A/B frag
typedef __attribute__((ext_vector_type(4))) float f32x4;   // MFMA C/D frag

#define DIM    1024
#define NHEADS 16
#define HD     64
#define NSEQ   2048
#define QKVN   3072

__device__ __forceinline__ u16 f2bf(float f) {
  u32 u = __float_as_uint(f);
  u += 0x7FFF + ((u >> 16) & 1);   // RNE
  return (u16)(u >> 16);
}

// raw v_exp_f32 (exp2). HIP's exp2f() is precise libm (~10 ops) — r3 regression.
__device__ __forceinline__ float vexp2(float x) {
  float r;
  asm volatile("v_exp_f32 %0, %1" : "=v"(r) : "v"(x));
  return r;
}

// async global->LDS, 16B per lane. LDS dst = wave-uniform base + lane*16.
__device__ __forceinline__ void async16(const u16* g, u16* l) {
  __builtin_amdgcn_global_load_lds(
      (const __attribute__((address_space(1))) unsigned int*)g,
      (__attribute__((address_space(3))) unsigned int*)l, 16, 0, 0);
}

// ---------------------------------------------------------------- cast fp32 -> bf16
__global__ void cast_all(const float* __restrict__ x, const float* __restrict__ wq,
                         const float* __restrict__ wp, u16* __restrict__ xo,
                         u16* __restrict__ wqo, u16* __restrict__ wpo) {
  int i = blockIdx.x * 256 + threadIdx.x;        // 2,097,152 threads, 4 floats each
  const float4* src; u16* dst; int off;
  if (i < 1048576)      { src = (const float4*)x;  dst = xo;  off = i; }
  else if (i < 1835008) { src = (const float4*)wq; dst = wqo; off = i - 1048576; }
  else                  { src = (const float4*)wp; dst = wpo; off = i - 1835008; }
  float4 f = src[off];
  ushort4 o;
  o.x = f2bf(f.x); o.y = f2bf(f.y); o.z = f2bf(f.z); o.w = f2bf(f.w);
  ((ushort4*)dst)[off] = o;
}

// ---------------------------------------------------------------- GEMM  C = A * B^T
// r3 structure (known-good): A [M,1024] bf16 K-major, B [N,1024] bf16 K-major.
// BK=64, async staging with XOR chunk swizzle c' = c ^ (row&7). 256 thr / 4 waves.
// FINAL=false: BM=128, grid 32x24; scalar coalesced Q,K stores -> qkv,
//              packed ushort4 V stores -> vt. FINAL=true: BM=64; out = C + bias.
template <bool FINAL>
__global__ __launch_bounds__(256, 3) void gemm_bt(
    const u16* __restrict__ A, const u16* __restrict__ Bw, u16* __restrict__ qkv,
    u16* __restrict__ vt, const float* __restrict__ bias, float* __restrict__ outp) {
  constexpr int K = 1024;
  constexpr int BM = FINAL ? 64 : 128;
  constexpr int MT = FINAL ? 64 : 32;
  constexpr int IT = FINAL ? 2 : 4;           // 16-row i-tiles per wave
  constexpr int ACALLS = BM / 8;              // wave-calls to stage A tile
  constexpr int TCALLS = ACALLS + 16;
  constexpr int PW = TCALLS / 4;              // calls per wave
  const int bm = blockIdx.x % MT;
  const int bn = blockIdx.x / MT;
  const int tid = threadIdx.x;
  const int wave = tid >> 6, lane = tid & 63;
  const int q4 = lane >> 4, l15 = lane & 15;
  const int wm = wave >> 1, wn = wave & 1;
  const int m0 = bm * BM, n0 = bn * 128;

  __shared__ alignas(16) u16 lsA[BM * 64];
  __shared__ alignas(16) u16 lsB[128 * 64];

  f32x4 acc[IT][4];
#pragma unroll
  for (int i = 0; i < IT; i++)
#pragma unroll
    for (int j = 0; j < 4; j++) acc[i][j] = (f32x4){0.f, 0.f, 0.f, 0.f};

  for (int k0 = 0; k0 < K; k0 += 64) {
    __syncthreads();
#pragma unroll
    for (int j = 0; j < PW; ++j) {
      int t = wave * PW + j;
      if (t < ACALLS) {
        int lin = t * 64 + lane;
        int r = lin >> 3, cs = lin & 7, c = cs ^ (r & 7);
        async16(A + (size_t)(m0 + r) * K + k0 + c * 8, lsA + t * 512);
      } else {
        int tb = t - ACALLS;
        int lin = tb * 64 + lane;
        int r = lin >> 3, cs = lin & 7, c = cs ^ (r & 7);
        async16(Bw + (size_t)(n0 + r) * K + k0 + c * 8, lsB + tb * 512);
      }
    }
    __syncthreads();
#pragma unroll
    for (int kc = 0; kc < 2; ++kc) {
      s16x8 af[IT], bfr[4];
#pragma unroll
      for (int i = 0; i < IT; ++i) {
        int r = wm * (IT * 16) + i * 16 + l15;
        int c = (kc * 4 + q4) ^ (r & 7);
        af[i] = *(const s16x8*)(lsA + r * 64 + c * 8);
      }
#pragma unroll
      for (int j = 0; j < 4; ++j) {
        int r = wn * 64 + j * 16 + l15;
        int c = (kc * 4 + q4) ^ (r & 7);
        bfr[j] = *(const s16x8*)(lsB + r * 64 + c * 8);
      }
#pragma unroll
      for (int i = 0; i < IT; ++i)
#pragma unroll
        for (int j = 0; j < 4; ++j)
          acc[i][j] = __builtin_amdgcn_mfma_f32_16x16x32_bf16(af[i], bfr[j], acc[i][j], 0, 0, 0);
    }
  }

  // epilogue: C/D layout col=lane&15, row=quad*4+reg
#pragma unroll
  for (int i = 0; i < IT; i++) {
#pragma unroll
    for (int j = 0; j < 4; j++) {
      int n = n0 + wn * 64 + j * 16 + l15;
      int mb = m0 + wm * (IT * 16) + i * 16 + q4 * 4;
      if (FINAL) {
#pragma unroll
        for (int r = 0; r < 4; r++)
          outp[(size_t)(mb + r) * DIM + n] = acc[i][j][r] + bias[n];
      } else if (n < 2048) {
#pragma unroll
        for (int r = 0; r < 4; r++)
          qkv[(size_t)(mb + r) * QKVN + n] = f2bf(acc[i][j][r]);
      } else {
        int b = mb >> 11, tok = mb & 2047;
        int h = (n >> 6) & 15, hd = n & 63;
        ushort4 pk;
        pk.x = f2bf(acc[i][j][0]); pk.y = f2bf(acc[i][j][1]);
        pk.z = f2bf(acc[i][j][2]); pk.w = f2bf(acc[i][j][3]);
        *(ushort4*)(vt + ((size_t)((b * NHEADS + h) * HD + hd)) * NSEQ + tok) = pk;
      }
    }
  }
}

// ---------------------------------------------------------------- flash attention
// 1024 blocks (blk = qt*32 + bh: same-bh blocks share an XCD -> K/V in L2),
// 256 thr / 4 waves x 16 q-rows (64 q-rows per block). 64-key staging tiles.
// 25 KB LDS -> 6 blocks/CU, 24 waves/CU cap; grid all-resident, no tail.
// exp2-domain softmax (Q pre-scaled by log2(e)/8, raw v_exp_f32). P truncated
// to bf16; lsum accumulates the truncated value (normalizer consistent with
// MFMA input -> no scale bias).
__global__ __launch_bounds__(256, 6) void attn_kernel(const u16* __restrict__ qkv,
                                                      const u16* __restrict__ vt,
                                                      u16* __restrict__ aout) {
  const int blk = blockIdx.x;            // 1024 = 32 qtiles * 32 bh (bh fast)
  const int bh = blk & 31, qt = blk >> 5;
  const int b = bh >> 4, h = bh & 15;
  const int tid = threadIdx.x;
  const int wave = tid >> 6, lane = tid & 63;
  const int q4 = lane >> 4, l15 = lane & 15;

  __shared__ alignas(16) u16 lsK[64 * 64];       // [key][hd], swizzled 16B chunks
  __shared__ alignas(16) u16 lsV[64 * 64];       // [hd][key], swizzled 16B chunks
  __shared__ alignas(16) u16 lsP[4][16 * 72];    // per-wave P [qrow][key], stride 72

  // Q A-frags in registers, pre-scaled by log2(e)/8 (f32 mul, RNE back to bf16)
  const float QSCALE = 0.18033688011112042f;     // log2(e)/8
  s16x8 aq[2];
#pragma unroll
  for (int kc = 0; kc < 2; ++kc) {
    int row = b * NSEQ + qt * 64 + wave * 16 + l15;
    uint4 d = *(const uint4*)(qkv + (size_t)row * QKVN + h * HD + kc * 32 + q4 * 8);
    u32 w[4] = {d.x, d.y, d.z, d.w};
    s16x8 f;
#pragma unroll
    for (int j = 0; j < 8; ++j) {
      u16 u = (u16)(w[j >> 1] >> ((j & 1) * 16));
      float v = __uint_as_float(((u32)u) << 16) * QSCALE;
      f[j] = (short)f2bf(v);
    }
    aq[kc] = f;
  }

  f32x4 o[4];
  float lsum[4] = {0.f, 0.f, 0.f, 0.f};
#pragma unroll
  for (int ht = 0; ht < 4; ++ht) o[ht] = (f32x4){0.f, 0.f, 0.f, 0.f};

  for (int kt = 0; kt < 32; ++kt) {              // 64 keys per staging tile
    __syncthreads();
#pragma unroll
    for (int j = 0; j < 2; ++j) {
      int t = wave * 2 + j;                      // t in 0..7: 8 calls per buffer
      int lin = t * 64 + lane;
      int r = lin >> 3, c = (lin & 7) ^ (r & 7);
      async16(qkv + (size_t)(b * NSEQ + kt * 64 + r) * QKVN + DIM + h * HD + c * 8,
              lsK + t * 512);
      async16(vt + (size_t)(bh * HD + r) * NSEQ + kt * 64 + c * 8,
              lsV + t * 512);
    }
    __syncthreads();

    // S = Q K^T  (16 q-rows x 64 keys per wave)
    f32x4 s[4];
#pragma unroll
    for (int ct = 0; ct < 4; ++ct) s[ct] = (f32x4){0.f, 0.f, 0.f, 0.f};
#pragma unroll
    for (int kc = 0; kc < 2; ++kc) {
#pragma unroll
      for (int ct = 0; ct < 4; ++ct) {
        int r = ct * 16 + l15;
        int c = (kc * 4 + q4) ^ (r & 7);
        s16x8 bk = *(const s16x8*)(lsK + r * 64 + c * 8);
        s[ct] = __builtin_amdgcn_mfma_f32_16x16x32_bf16(aq[kc], bk, s[ct], 0, 0, 0);
      }
    }

    // p = exp2(s) via raw v_exp_f32; truncate to bf16; lsum sums truncated value
#pragma unroll
    for (int ct = 0; ct < 4; ++ct)
#pragma unroll
      for (int r = 0; r < 4; ++r) {
        u32 u = __float_as_uint(vexp2(s[ct][r]));
        lsum[r] += __uint_as_float(u & 0xffff0000u);
        lsP[wave][(q4 * 4 + r) * 72 + ct * 16 + l15] = (u16)(u >> 16);
      }

    // O += P * V
#pragma unroll
    for (int kc = 0; kc < 2; ++kc) {
      s16x8 pa = *(const s16x8*)(lsP[wave] + l15 * 72 + kc * 32 + q4 * 8);
#pragma unroll
      for (int ht = 0; ht < 4; ++ht) {
        int r = ht * 16 + l15;
        int c = (kc * 4 + q4) ^ (r & 7);
        s16x8 vb = *(const s16x8*)(lsV + r * 64 + c * 8);
        o[ht] = __builtin_amdgcn_mfma_f32_16x16x32_bf16(pa, vb, o[ht], 0, 0, 0);
      }
    }
  }

  // final row-sum reduction over the 16 l15 lanes
#pragma unroll
  for (int off = 1; off < 16; off <<= 1)
#pragma unroll
    for (int r = 0; r < 4; ++r) lsum[r] += __shfl_xor(lsum[r], off, 64);
  float inv[4];
#pragma unroll
  for (int r = 0; r < 4; ++r) inv[r] = 1.0f / lsum[r];

#pragma unroll
  for (int ht = 0; ht < 4; ++ht)
#pragma unroll
    for (int r = 0; r < 4; ++r) {
      int n = qt * 64 + wave * 16 + q4 * 4 + r;
      int col = h * HD + ht * 16 + l15;
      aout[(size_t)(b * NSEQ + n) * DIM + col] = f2bf(o[ht][r] * inv[r]);
    }
}

// ---------------------------------------------------------------- launch
extern "C" void kernel_launch(void* const* d_in, const int* in_sizes, int n_in,
                              void* d_out, int out_size, void* d_ws, size_t ws_size,
                              hipStream_t stream) {
  const float* x     = (const float*)d_in[0];
  const float* w_qkv = (const float*)d_in[1];
  const float* w_prj = (const float*)d_in[2];
  const float* b_prj = (const float*)d_in[3];
  float* out = (float*)d_out;

  char* ws = (char*)d_ws;
  u16* x_bf    = (u16*)(ws);                          // 8 MB
  u16* wqkv_bf = (u16*)(ws + (size_t)(8u << 20));     // 6 MB
  u16* wprj_bf = (u16*)(ws + (size_t)(14u << 20));    // 2 MB
  u16* qkv     = (u16*)(ws + (size_t)(16u << 20));    // 24 MB (Q,K used; V slot unused)
  u16* vt      = (u16*)(ws + (size_t)(40u << 20));    // 8 MB
  u16* aout    = (u16*)(ws + (size_t)(48u << 20));    // 8 MB   total 56 MB

  cast_all<<<8192, 256, 0, stream>>>(x, w_qkv, w_prj, x_bf, wqkv_bf, wprj_bf);
  gemm_bt<false><<<32 * 24, 256, 0, stream>>>(x_bf, wqkv_bf, qkv, vt, nullptr, nullptr);
  attn_kernel<<<1024, 256, 0, stream>>>(qkv, vt, aout);
  gemm_bt<true><<<64 * 8, 256, 0, stream>>>(aout, wprj_bf, nullptr, nullptr, b_prj, out);
}